// Round 1
// baseline (246.985 us; speedup 1.0000x reference)
//
#include <hip/hip_runtime.h>
#include <hip/hip_bf16.h>

typedef unsigned short u16;

#define B_      8
#define N_      1025
#define D_      768
#define H_      12
#define HD_     64
#define M_REAL  (B_ * N_)      /* 8200 rows */
#define M_PAD   8320           /* 65 * 128 */
#define QKVC    (3 * D_)       /* 2304 */

typedef __attribute__((ext_vector_type(8))) short bf16x8;
typedef __attribute__((ext_vector_type(4))) float f32x4;

static __device__ __forceinline__ float bf2f(u16 u) {
    union { unsigned int i; float f; } v; v.i = ((unsigned int)u) << 16; return v.f;
}
static __device__ __forceinline__ u16 f2bf(float f) {
    union { float f; unsigned int i; } v; v.f = f;
    unsigned int x = v.i;
    return (u16)((x + 0x7fffu + ((x >> 16) & 1u)) >> 16);   /* RNE */
}
static __device__ __forceinline__ unsigned int cvtpk(float a, float b) {
    unsigned int r;
    asm volatile("v_cvt_pk_bf16_f32 %0, %1, %2" : "=v"(r) : "v"(a), "v"(b));
    return r;   /* lo = bf16(a), hi = bf16(b) */
}

/* async global->LDS, 16B per lane; LDS dest = wave-uniform base + lane*16 */
static __device__ __forceinline__ void g2l16(const u16* g, u16* l) {
    __builtin_amdgcn_global_load_lds(
        (const __attribute__((address_space(1))) unsigned int*)g,
        (__attribute__((address_space(3))) unsigned int*)l, 16, 0, 0);
}

/* ------- fused LayerNorm (rows) + fp32->bf16 weight convert (tail) ------- */
__global__ __launch_bounds__(256)
void ln_f2b_kernel(const float* __restrict__ x, const float* __restrict__ g,
                   const float* __restrict__ bvec, u16* __restrict__ xn,
                   const float* __restrict__ wq, u16* __restrict__ wqb,
                   const float* __restrict__ wp, u16* __restrict__ wpb)
{
    const int tid = threadIdx.x;
    if (blockIdx.x >= M_REAL) {
        /* weight convert: 1024 elems per block */
        int i = (blockIdx.x - M_REAL) * 1024 + tid * 4;
        const float* src; u16* dst;
        if (i < QKVC * D_) { src = wq + i; dst = wqb + i; }
        else { src = wp + (i - QKVC * D_); dst = wpb + (i - QKVC * D_); }
        float4 v = *(const float4*)src;
        dst[0] = f2bf(v.x); dst[1] = f2bf(v.y);
        dst[2] = f2bf(v.z); dst[3] = f2bf(v.w);
        return;
    }
    const int row = blockIdx.x;
    const float* xr = x + (size_t)row * D_;
    float v[3];
    float s = 0.f, ss = 0.f;
#pragma unroll
    for (int j = 0; j < 3; j++) {
        float val = xr[tid + j * 256];
        v[j] = val; s += val; ss += val * val;
    }
    __shared__ float r1[256], r2[256];
    r1[tid] = s; r2[tid] = ss; __syncthreads();
    for (int off = 128; off > 0; off >>= 1) {
        if (tid < off) { r1[tid] += r1[tid + off]; r2[tid] += r2[tid + off]; }
        __syncthreads();
    }
    const float mean = r1[0] * (1.0f / D_);
    const float var  = r2[0] * (1.0f / D_) - mean * mean;
    const float rs   = rsqrtf(var + 1e-5f);
    u16* outr = xn + (size_t)row * D_;
#pragma unroll
    for (int j = 0; j < 3; j++) {
        int c = tid + j * 256;
        outr[c] = f2bf((v[j] - mean) * rs * g[c] + bvec[c]);
    }
}

/* -------- GEMM: C[m][n] = sum_k A[m][k] * B[n][k] (+bias fp32) --------
   128x128 tile, BK=32, 4 waves (2x2), MFMA f32_16x16x32_bf16.
   Double-buffered async staging (global_load_lds w=16), one barrier per
   K-iteration. Epilogue through LDS for full-line coalesced stores.
   ROPE fuses 2D rope (QKV output) AND the 1/8 attention scale on Q
   (exact exponent shift -> bit-identical to scaling at attention time);
   XCD patch-swizzle for L2 locality.                                    */
template <typename OutT, bool ROPE>
__global__ __launch_bounds__(256)
void gemm_bt(const u16* __restrict__ A, const u16* __restrict__ B,
             OutT* __restrict__ C, const float* __restrict__ bias,
             int M_real, int Ncols, int K,
             int BM, int BN, int gh, int gw, int PC)
{
    const int l   = blockIdx.x;
    const int xcd = l & 7;
    const int i0  = l >> 3;
    const int pr  = xcd / PC, pc = xcd % PC;
    const int bm  = pr * gh + (i0 % gh);
    const int bn  = pc * gw + (i0 / gh);
    if (bm >= BM || bn >= BN) return;

    __shared__ __align__(16) unsigned char smem[34816];
    u16* As0 = (u16*)smem;              /* 128 x 32 */
    u16* Bs0 = (u16*)(smem + 8192);
    u16*   ep16 = (u16*)smem;           /* 128 x 136 (pad 8) */
    float* ep32 = (float*)smem;         /* 64 x 132 (pad 4)  */

    const int tid  = threadIdx.x;
    const int wave = tid >> 6, lane = tid & 63;
    const int wm   = (wave >> 1) * 64, wn = (wave & 1) * 64;
    const int lrow = lane & 15, lq = lane >> 4;
    const int lrow4 = lane >> 2, lchunk = lane & 3;

    int ar0 = bm * 128 + wave * 16 + lrow4;       if (ar0 >= M_real) ar0 = M_real - 1;
    int ar1 = bm * 128 + (wave + 4) * 16 + lrow4; if (ar1 >= M_real) ar1 = M_real - 1;
    const u16* apg0 = A + (size_t)ar0 * K + lchunk * 8;
    const u16* apg1 = A + (size_t)ar1 * K + lchunk * 8;
    const u16* bpg0 = B + (size_t)(bn * 128 + wave * 16 + lrow4) * K + lchunk * 8;
    const u16* bpg1 = B + (size_t)(bn * 128 + (wave + 4) * 16 + lrow4) * K + lchunk * 8;
    u16* asl0 = As0 + wave * 512;       u16* asl1 = As0 + (wave + 4) * 512;
    u16* bsl0 = Bs0 + wave * 512;       u16* bsl1 = Bs0 + (wave + 4) * 512;
    const int bufoff = 8192;

    f32x4 acc[4][4];
#pragma unroll
    for (int i = 0; i < 4; i++)
#pragma unroll
        for (int j = 0; j < 4; j++)
            acc[i][j] = (f32x4){0.f, 0.f, 0.f, 0.f};

    g2l16(apg0, asl0); g2l16(apg1, asl1);
    g2l16(bpg0, bsl0); g2l16(bpg1, bsl1);

    const int kTiles = K / 32;
    for (int kt = 0; kt < kTiles; kt++) {
        const int cur = kt & 1;
        __syncthreads();
        if (kt + 1 < kTiles) {
            const int k1 = (kt + 1) * 32;
            const int no = (cur ^ 1) * bufoff;
            g2l16(apg0 + k1, asl0 + no); g2l16(apg1 + k1, asl1 + no);
            g2l16(bpg0 + k1, bsl0 + no); g2l16(bpg1 + k1, bsl1 + no);
        }
        const u16* Asr = As0 + cur * bufoff;
        const u16* Bsr = Bs0 + cur * bufoff;
        bf16x8 af[4], bfr[4];
#pragma unroll
        for (int i = 0; i < 4; i++) {
            af[i]  = *(const bf16x8*)&Asr[(wm + i * 16 + lrow) * 32 + lq * 8];
            bfr[i] = *(const bf16x8*)&Bsr[(wn + i * 16 + lrow) * 32 + lq * 8];
        }
#pragma unroll
        for (int i = 0; i < 4; i++)
#pragma unroll
            for (int j = 0; j < 4; j++)
                acc[i][j] = __builtin_amdgcn_mfma_f32_16x16x32_bf16(af[i], bfr[j], acc[i][j], 0, 0, 0);
    }
    __syncthreads();

    if constexpr (sizeof(OutT) == 2) {
#pragma unroll
        for (int j = 0; j < 4; j++) {
            int gcol = bn * 128 + wn + j * 16 + lrow;
            float bv = bias ? bias[gcol] : 0.f;
            int qk = gcol / D_;
            int dh = gcol & 63;
            int half = dh >> 5, ii = (dh & 31) >> 1;
            float sgn = (dh & 1) ? 1.f : -1.f;
            float invf = exp2f(-(float)ii * 0.8304820237218406f);
#pragma unroll
            for (int i = 0; i < 4; i++)
#pragma unroll
                for (int r = 0; r < 4; r++) {
                    int grow = bm * 128 + wm + i * 16 + lq * 4 + r;
                    float val = acc[i][j][r] + bv;
                    if constexpr (ROPE) {
                        if (qk < 2) {
                            float partner = __shfl_xor(val, 1);
                            int n = grow % N_;
                            int pl = n - 1;
                            int pos = (n == 0) ? 0 : (half ? (pl & 31) : (pl >> 5));
                            float ang = (float)pos * invf;
                            val = val * __cosf(ang) + sgn * partner * __sinf(ang);
                            if (qk == 0) val *= 0.125f;   /* fold 1/sqrt(hd) into Q (exact) */
                        }
                    }
                    ep16[(wm + i * 16 + lq * 4 + r) * 136 + wn + j * 16 + lrow] = f2bf(val);
                }
        }
        __syncthreads();
#pragma unroll
        for (int c = 0; c < 8; c++) {
            int idx = tid + c * 256;
            int row = idx >> 4, l16 = idx & 15;
            int grow = bm * 128 + row;
            if (grow < M_real)
                *(uint4*)((u16*)C + (size_t)grow * Ncols + bn * 128 + l16 * 8) =
                    *(const uint4*)&ep16[row * 136 + l16 * 8];
        }
    } else {
#pragma unroll
        for (int s = 0; s < 2; s++) {
            if (s) __syncthreads();
            if (wm == s * 64) {
#pragma unroll
                for (int j = 0; j < 4; j++) {
                    int gcol = bn * 128 + wn + j * 16 + lrow;
                    float bv = bias ? bias[gcol] : 0.f;
#pragma unroll
                    for (int i = 0; i < 4; i++)
#pragma unroll
                        for (int r = 0; r < 4; r++)
                            ep32[(i * 16 + lq * 4 + r) * 132 + wn + j * 16 + lrow] =
                                acc[i][j][r] + bv;
                }
            }
            __syncthreads();
#pragma unroll
            for (int c = 0; c < 8; c++) {
                int idx = tid + c * 256;
                int row = idx >> 5, l32 = idx & 31;
                int grow = bm * 128 + s * 64 + row;
                if (grow < M_real)
                    *(uint4*)((float*)C + (size_t)grow * Ncols + bn * 128 + l32 * 4) =
                        *(const uint4*)&ep32[row * 132 + l32 * 4];
            }
        }
    }
}

/* -------- MFMA flash attention v5: K direct-from-global, P in registers --
   1D grid, XCD-swizzled: xcd = l & 7 owns 12 whole (b,h) heads.
   Block = (b,h) x 128 queries, 4 waves x 32 queries. Per 64-key tile:
   - K fragments loaded straight from global into regs (L2-resident per
     XCD head-group), prefetched one tile ahead. No Kt in LDS.
   - V register-prefetched, transposed into double-buffered Vt[2][64][72]
     with the key COLUMN PERMUTED to kslot order (see below).
   - S^T = K (Q/8)^T: A = K reg-frags, B = Q regs (Q pre-scaled by 1/8 in
     the QKV GEMM epilogue). C gives lane (lm,lq) keys st*16+lq*4+r.
   - Key permutation kslot(32a+16b+4c+r) = 32a+8c+4b+r makes the S^T
     output layout EQUAL the PV A-operand layout -> P never touches LDS:
     16 x v_cvt_pk_bf16_f32 builds pa[][] in-register.  V columns are
     written at vcol = kslot(key) so PV's B-operand sees the same order.
   - One raw s_barrier per tile (lgkmcnt(0) only -> K/V global prefetch
     stays in flight across it); Vt double-buffer makes this sufficient.
   Scores bounded (|s|<~4): fixed-max-0 softmax; l per-lane (q=lm),
   quad-reduced + LDS broadcast once at the end.                          */
__global__ __launch_bounds__(256)
void attn_mfma(const u16* __restrict__ qkv, u16* __restrict__ out)
{
    __shared__ __align__(16) u16 Vt[2][64][72];
    __shared__ float Lw[4][32];

    const int l   = blockIdx.x;
    const int xcd = l & 7;
    const int j0  = l >> 3;            /* 0..107 */
    const int bh  = xcd * 12 + j0 / 9; /* 12 heads per XCD */
    const int b  = bh / H_, h = bh % H_;
    const int q0 = (j0 % 9) * 128;
    const int tid  = threadIdx.x;
    const int wave = tid >> 6, lane = tid & 63;
    const int lm = lane & 15, lq = lane >> 4;
    const int qw = q0 + wave * 32;

    /* key -> kslot permutation: key = 32a+16b+4c+r  ->  32a+8c+4b+r */
    const int vcol = (lane & 35) | ((lane & 12) << 1) | ((lane & 16) >> 2);

    /* Q fragments (B-operand: n=q=lm, k=d=lq*8+j); 1/8 scale already baked */
    bf16x8 qf[2][2];
#pragma unroll
    for (int sq = 0; sq < 2; sq++) {
        int qrow = qw + sq * 16 + lm; if (qrow > N_ - 1) qrow = N_ - 1;
        const u16* qptr = qkv + (size_t)(b * N_ + qrow) * QKVC + h * HD_;
        qf[sq][0] = *(const bf16x8*)(qptr + lq * 8);
        qf[sq][1] = *(const bf16x8*)(qptr + 32 + lq * 8);
    }

    const u16* kb_ptr = qkv + (size_t)b * N_ * QKVC + D_ + h * HD_ + lq * 8;
    const u16* vb_ptr = qkv + (size_t)b * N_ * QKVC + 2 * D_ + h * HD_ + wave * 8;

    float l_r[2] = {0.f, 0.f};
    f32x4 o_acc[2][4];
#pragma unroll
    for (int sq = 0; sq < 2; sq++)
#pragma unroll
        for (int t = 0; t < 4; t++)
            o_acc[sq][t] = (f32x4){0.f, 0.f, 0.f, 0.f};

    /* prefetch tile 0 into registers */
    bf16x8 kf[4][2], vreg[2];
#pragma unroll
    for (int st = 0; st < 4; st++) {
        const u16* p = kb_ptr + (size_t)(st * 16 + lm) * QKVC;
        kf[st][0] = *(const bf16x8*)p;
        kf[st][1] = *(const bf16x8*)(p + 32);
    }
    {
        const u16* p = vb_ptr + (size_t)lane * QKVC;
        vreg[0] = *(const bf16x8*)p;
        vreg[1] = *(const bf16x8*)(p + 32);
    }

    const int kTiles = (N_ + 63) / 64;   /* 17 */
    for (int kt = 0; kt < kTiles; kt++) {
        const int kbase = kt * 64;
        const int buf = kt & 1;

        /* V tile -> LDS transposed [d][kslot] (column-permuted) */
#pragma unroll
        for (int pp = 0; pp < 2; pp++) {
            int dg = wave + pp * 4;
#pragma unroll
            for (int j = 0; j < 8; j++)
                Vt[buf][dg * 8 + j][vcol] = (u16)vreg[pp][j];
        }

        /* S^T = K (Q/8)^T : A = K reg-frags, B = Q regs.
           C: col=lm=q_local, row=lq*4+r=key st*16+lq*4+r.              */
        f32x4 sc[2][4];
        __builtin_amdgcn_s_setprio(1);
#pragma unroll
        for (int st = 0; st < 4; st++)
#pragma unroll
            for (int sq = 0; sq < 2; sq++) {
                f32x4 s4 = (f32x4){0.f, 0.f, 0.f, 0.f};
                s4 = __builtin_amdgcn_mfma_f32_16x16x32_bf16(kf[st][0], qf[sq][0], s4, 0, 0, 0);
                s4 = __builtin_amdgcn_mfma_f32_16x16x32_bf16(kf[st][1], qf[sq][1], s4, 0, 0, 0);
                sc[sq][st] = s4;
            }
        __builtin_amdgcn_s_setprio(0);

        /* register prefetch of next K,V tile (kf/vreg now dead) */
        if (kt + 1 < kTiles) {
            const int kb = kbase + 64;
#pragma unroll
            for (int st = 0; st < 4; st++) {
                int kr = kb + st * 16 + lm; if (kr > N_ - 1) kr = N_ - 1;
                const u16* p = kb_ptr + (size_t)kr * QKVC;
                kf[st][0] = *(const bf16x8*)p;
                kf[st][1] = *(const bf16x8*)(p + 32);
            }
            int kr = kb + lane; if (kr > N_ - 1) kr = N_ - 1;
            const u16* p = vb_ptr + (size_t)kr * QKVC;
            vreg[0] = *(const bf16x8*)p;
            vreg[1] = *(const bf16x8*)(p + 32);
        }

        /* Vt writes visible to all waves; global prefetch stays in flight */
        asm volatile("s_waitcnt lgkmcnt(0)" ::: "memory");
        __builtin_amdgcn_s_barrier();

        /* softmax (fixed max 0) + in-register pack straight into the PV
           A-operand order (kslot permutation makes layouts coincide).   */
        const bool lastT = (kt == kTiles - 1);
        bf16x8 pa[2][2];
#pragma unroll
        for (int sq = 0; sq < 2; sq++) {
            union { bf16x8 v; unsigned int u[4]; } pk0, pk1;
#pragma unroll
            for (int st = 0; st < 4; st++) {
                float p0 = __expf(sc[sq][st][0]);
                float p1 = __expf(sc[sq][st][1]);
                float p2 = __expf(sc[sq][st][2]);
                float p3 = __expf(sc[sq][st][3]);
                if (lastT) {
                    const int keyb = kbase + st * 16 + lq * 4;
                    if (keyb + 0 >= N_) p0 = 0.f;
                    if (keyb + 1 >= N_) p1 = 0.f;
                    if (keyb + 2 >= N_) p2 = 0.f;
                    if (keyb + 3 >= N_) p3 = 0.f;
                }
                l_r[sq] += (p0 + p1) + (p2 + p3);
                unsigned int lo = cvtpk(p0, p1);
                unsigned int hi = cvtpk(p2, p3);
                if      (st == 0) { pk0.u[0] = lo; pk0.u[1] = hi; }
                else if (st == 1) { pk0.u[2] = lo; pk0.u[3] = hi; }
                else if (st == 2) { pk1.u[0] = lo; pk1.u[1] = hi; }
                else              { pk1.u[2] = lo; pk1.u[3] = hi; }
            }
            pa[sq][0] = pk0.v; pa[sq][1] = pk1.v;
        }

        /* PV: A = packed P regs, B = Vt rows (b128, kslot columns) */
        __builtin_amdgcn_s_setprio(1);
#pragma unroll
        for (int nt = 0; nt < 4; nt++) {
            bf16x8 vb0 = *(const bf16x8*)&Vt[buf][nt * 16 + lm][lq * 8];
            bf16x8 vb1 = *(const bf16x8*)&Vt[buf][nt * 16 + lm][32 + lq * 8];
#pragma unroll
            for (int sq = 0; sq < 2; sq++) {
                o_acc[sq][nt] = __builtin_amdgcn_mfma_f32_16x16x32_bf16(pa[sq][0], vb0, o_acc[sq][nt], 0, 0, 0);
                o_acc[sq][nt] = __builtin_amdgcn_mfma_f32_16x16x32_bf16(pa[sq][1], vb1, o_acc[sq][nt], 0, 0, 0);
            }
        }
        __builtin_amdgcn_s_setprio(0);
    }

    /* l: reduce across quads (lane holds q=sq*16+lm partial), broadcast */
#pragma unroll
    for (int sq = 0; sq < 2; sq++) {
        float l2 = l_r[sq];
        l2 += __shfl_xor(l2, 16);
        l2 += __shfl_xor(l2, 32);
        if (lq == 0) Lw[wave][sq * 16 + lm] = l2;
    }
    asm volatile("s_waitcnt lgkmcnt(0)" ::: "memory");       /* wave-local */

    /* store: O layout col=d=nt*16+lm, row=q=sq*16+lq*4+r */
#pragma unroll
    for (int sq = 0; sq < 2; sq++)
#pragma unroll
        for (int r = 0; r < 4; r++) {
            int q = qw + sq * 16 + lq * 4 + r;
            if (q < N_) {
                float inv = 1.0f / Lw[wave][sq * 16 + lq * 4 + r];
                u16* orow = out + (size_t)(b * N_ + q) * D_ + h * HD_ + lm;
#pragma unroll
                for (int nt = 0; nt < 4; nt++)
                    orow[nt * 16] = f2bf(o_acc[sq][nt][r] * inv);
            }
        }
}

extern "C" void kernel_launch(void* const* d_in, const int* in_sizes, int n_in,
                              void* d_out, int out_size, void* d_ws, size_t ws_size,
                              hipStream_t stream)
{
    const float* x      = (const float*)d_in[0];
    const float* ln_g   = (const float*)d_in[1];
    const float* ln_b   = (const float*)d_in[2];
    const float* w_qkv  = (const float*)d_in[3];
    const float* w_proj = (const float*)d_in[4];
    const float* b_proj = (const float*)d_in[5];

    u16* wqkv_b  = (u16*)d_ws;                         /* 2304*768  */
    u16* wproj_b = wqkv_b + (size_t)QKVC * D_;         /* 768*768   */
    u16* xn      = wproj_b + (size_t)D_ * D_;          /* M_PAD*768 */
    u16* qkv     = xn + (size_t)M_PAD * D_;            /* M_PAD*2304 */
    u16* attno   = xn;                                 /* alias (xn dead after QKV GEMM) */

    /* fused LN + weight convert: 8200 LN blocks + 2304 convert blocks */
    ln_f2b_kernel<<<M_REAL + (QKVC * D_ + D_ * D_) / 1024, 256, 0, stream>>>(
        x, ln_g, ln_b, xn, w_qkv, wqkv_b, w_proj, wproj_b);

    /* QKV GEMM: BM=65, BN=18; 4x2 XCD patches of 17x9 -> 1224 blocks */
    gemm_bt<u16, true><<<1224, 256, 0, stream>>>(
        xn, wqkv_b, qkv, nullptr, M_REAL, QKVC, D_,
        65, 18, 17, 9, 2);

    /* attention: 8 XCDs x 12 heads x 9 q-tiles = 864 blocks */
    attn_mfma<<<864, 256, 0, stream>>>(qkv, attno);

    /* proj GEMM: BM=65, BN=6; 8x1 XCD patches of 9x6 -> 432 blocks */
    gemm_bt<float, false><<<432, 256, 0, stream>>>(
        attno, wproj_b, (float*)d_out, b_proj, M_REAL, D_, D_,
        65, 6, 9, 6, 1);
}

// Round 2
// 214.737 us; speedup vs baseline: 1.1502x; 1.1502x over previous
//
#include <hip/hip_runtime.h>
#include <hip/hip_bf16.h>

typedef unsigned short u16;

#define B_      8
#define N_      1025
#define D_      768
#define H_      12
#define HD_     64
#define M_REAL  (B_ * N_)      /* 8200 rows */
#define M_PAD   8320           /* 65 * 128 */
#define QKVC    (3 * D_)       /* 2304 */

typedef __attribute__((ext_vector_type(8))) short bf16x8;
typedef __attribute__((ext_vector_type(4))) float f32x4;

static __device__ __forceinline__ float bf2f(u16 u) {
    union { unsigned int i; float f; } v; v.i = ((unsigned int)u) << 16; return v.f;
}
static __device__ __forceinline__ u16 f2bf(float f) {
    union { float f; unsigned int i; } v; v.f = f;
    unsigned int x = v.i;
    return (u16)((x + 0x7fffu + ((x >> 16) & 1u)) >> 16);   /* RNE */
}
static __device__ __forceinline__ unsigned int cvtpk(float a, float b) {
    unsigned int r;
    asm volatile("v_cvt_pk_bf16_f32 %0, %1, %2" : "=v"(r) : "v"(a), "v"(b));
    return r;   /* lo = bf16(a), hi = bf16(b) */
}

/* async global->LDS, 16B per lane; LDS dest = wave-uniform base + lane*16 */
static __device__ __forceinline__ void g2l16(const u16* g, u16* l) {
    __builtin_amdgcn_global_load_lds(
        (const __attribute__((address_space(1))) unsigned int*)g,
        (__attribute__((address_space(3))) unsigned int*)l, 16, 0, 0);
}

/* ------- fused LayerNorm (rows) + fp32->bf16 weight convert (tail) ------- */
__global__ __launch_bounds__(256)
void ln_f2b_kernel(const float* __restrict__ x, const float* __restrict__ g,
                   const float* __restrict__ bvec, u16* __restrict__ xn,
                   const float* __restrict__ wq, u16* __restrict__ wqb,
                   const float* __restrict__ wp, u16* __restrict__ wpb)
{
    const int tid = threadIdx.x;
    if (blockIdx.x >= M_REAL) {
        /* weight convert: 1024 elems per block */
        int i = (blockIdx.x - M_REAL) * 1024 + tid * 4;
        const float* src; u16* dst;
        if (i < QKVC * D_) { src = wq + i; dst = wqb + i; }
        else { src = wp + (i - QKVC * D_); dst = wpb + (i - QKVC * D_); }
        float4 v = *(const float4*)src;
        dst[0] = f2bf(v.x); dst[1] = f2bf(v.y);
        dst[2] = f2bf(v.z); dst[3] = f2bf(v.w);
        return;
    }
    const int row = blockIdx.x;
    const float* xr = x + (size_t)row * D_;
    float v[3];
    float s = 0.f, ss = 0.f;
#pragma unroll
    for (int j = 0; j < 3; j++) {
        float val = xr[tid + j * 256];
        v[j] = val; s += val; ss += val * val;
    }
    __shared__ float r1[256], r2[256];
    r1[tid] = s; r2[tid] = ss; __syncthreads();
    for (int off = 128; off > 0; off >>= 1) {
        if (tid < off) { r1[tid] += r1[tid + off]; r2[tid] += r2[tid + off]; }
        __syncthreads();
    }
    const float mean = r1[0] * (1.0f / D_);
    const float var  = r2[0] * (1.0f / D_) - mean * mean;
    const float rs   = rsqrtf(var + 1e-5f);
    u16* outr = xn + (size_t)row * D_;
#pragma unroll
    for (int j = 0; j < 3; j++) {
        int c = tid + j * 256;
        outr[c] = f2bf((v[j] - mean) * rs * g[c] + bvec[c]);
    }
}

/* -------- GEMM: C[m][n] = sum_k A[m][k] * B[n][k] (+bias fp32) --------
   128x128 tile, BK=32, 4 waves (2x2), MFMA f32_16x16x32_bf16.
   Double-buffered async staging (global_load_lds w=16), one barrier per
   K-iteration. Epilogue through LDS for full-line coalesced stores.
   ROPE fuses 2D rope (QKV output) AND the 1/8 attention scale on Q
   (exact exponent shift -> bit-identical to scaling at attention time);
   XCD patch-swizzle for L2 locality.                                    */
template <typename OutT, bool ROPE>
__global__ __launch_bounds__(256)
void gemm_bt(const u16* __restrict__ A, const u16* __restrict__ B,
             OutT* __restrict__ C, const float* __restrict__ bias,
             int M_real, int Ncols, int K,
             int BM, int BN, int gh, int gw, int PC)
{
    const int l   = blockIdx.x;
    const int xcd = l & 7;
    const int i0  = l >> 3;
    const int pr  = xcd / PC, pc = xcd % PC;
    const int bm  = pr * gh + (i0 % gh);
    const int bn  = pc * gw + (i0 / gh);
    if (bm >= BM || bn >= BN) return;

    __shared__ __align__(16) unsigned char smem[34816];
    u16* As0 = (u16*)smem;              /* 128 x 32 */
    u16* Bs0 = (u16*)(smem + 8192);
    u16*   ep16 = (u16*)smem;           /* 128 x 136 (pad 8) */
    float* ep32 = (float*)smem;         /* 64 x 132 (pad 4)  */

    const int tid  = threadIdx.x;
    const int wave = tid >> 6, lane = tid & 63;
    const int wm   = (wave >> 1) * 64, wn = (wave & 1) * 64;
    const int lrow = lane & 15, lq = lane >> 4;
    const int lrow4 = lane >> 2, lchunk = lane & 3;

    int ar0 = bm * 128 + wave * 16 + lrow4;       if (ar0 >= M_real) ar0 = M_real - 1;
    int ar1 = bm * 128 + (wave + 4) * 16 + lrow4; if (ar1 >= M_real) ar1 = M_real - 1;
    const u16* apg0 = A + (size_t)ar0 * K + lchunk * 8;
    const u16* apg1 = A + (size_t)ar1 * K + lchunk * 8;
    const u16* bpg0 = B + (size_t)(bn * 128 + wave * 16 + lrow4) * K + lchunk * 8;
    const u16* bpg1 = B + (size_t)(bn * 128 + (wave + 4) * 16 + lrow4) * K + lchunk * 8;
    u16* asl0 = As0 + wave * 512;       u16* asl1 = As0 + (wave + 4) * 512;
    u16* bsl0 = Bs0 + wave * 512;       u16* bsl1 = Bs0 + (wave + 4) * 512;
    const int bufoff = 8192;

    f32x4 acc[4][4];
#pragma unroll
    for (int i = 0; i < 4; i++)
#pragma unroll
        for (int j = 0; j < 4; j++)
            acc[i][j] = (f32x4){0.f, 0.f, 0.f, 0.f};

    g2l16(apg0, asl0); g2l16(apg1, asl1);
    g2l16(bpg0, bsl0); g2l16(bpg1, bsl1);

    const int kTiles = K / 32;
    for (int kt = 0; kt < kTiles; kt++) {
        const int cur = kt & 1;
        __syncthreads();
        if (kt + 1 < kTiles) {
            const int k1 = (kt + 1) * 32;
            const int no = (cur ^ 1) * bufoff;
            g2l16(apg0 + k1, asl0 + no); g2l16(apg1 + k1, asl1 + no);
            g2l16(bpg0 + k1, bsl0 + no); g2l16(bpg1 + k1, bsl1 + no);
        }
        const u16* Asr = As0 + cur * bufoff;
        const u16* Bsr = Bs0 + cur * bufoff;
        bf16x8 af[4], bfr[4];
#pragma unroll
        for (int i = 0; i < 4; i++) {
            af[i]  = *(const bf16x8*)&Asr[(wm + i * 16 + lrow) * 32 + lq * 8];
            bfr[i] = *(const bf16x8*)&Bsr[(wn + i * 16 + lrow) * 32 + lq * 8];
        }
#pragma unroll
        for (int i = 0; i < 4; i++)
#pragma unroll
            for (int j = 0; j < 4; j++)
                acc[i][j] = __builtin_amdgcn_mfma_f32_16x16x32_bf16(af[i], bfr[j], acc[i][j], 0, 0, 0);
    }
    __syncthreads();

    if constexpr (sizeof(OutT) == 2) {
#pragma unroll
        for (int j = 0; j < 4; j++) {
            int gcol = bn * 128 + wn + j * 16 + lrow;
            float bv = bias ? bias[gcol] : 0.f;
            int qk = gcol / D_;
            int dh = gcol & 63;
            int half = dh >> 5, ii = (dh & 31) >> 1;
            float sgn = (dh & 1) ? 1.f : -1.f;
            float invf = exp2f(-(float)ii * 0.8304820237218406f);
#pragma unroll
            for (int i = 0; i < 4; i++)
#pragma unroll
                for (int r = 0; r < 4; r++) {
                    int grow = bm * 128 + wm + i * 16 + lq * 4 + r;
                    float val = acc[i][j][r] + bv;
                    if constexpr (ROPE) {
                        if (qk < 2) {
                            float partner = __shfl_xor(val, 1);
                            int n = grow % N_;
                            int pl = n - 1;
                            int pos = (n == 0) ? 0 : (half ? (pl & 31) : (pl >> 5));
                            float ang = (float)pos * invf;
                            val = val * __cosf(ang) + sgn * partner * __sinf(ang);
                            if (qk == 0) val *= 0.125f;   /* fold 1/sqrt(hd) into Q (exact) */
                        }
                    }
                    ep16[(wm + i * 16 + lq * 4 + r) * 136 + wn + j * 16 + lrow] = f2bf(val);
                }
        }
        __syncthreads();
#pragma unroll
        for (int c = 0; c < 8; c++) {
            int idx = tid + c * 256;
            int row = idx >> 4, l16 = idx & 15;
            int grow = bm * 128 + row;
            if (grow < M_real)
                *(uint4*)((u16*)C + (size_t)grow * Ncols + bn * 128 + l16 * 8) =
                    *(const uint4*)&ep16[row * 136 + l16 * 8];
        }
    } else {
#pragma unroll
        for (int s = 0; s < 2; s++) {
            if (s) __syncthreads();
            if (wm == s * 64) {
#pragma unroll
                for (int j = 0; j < 4; j++) {
                    int gcol = bn * 128 + wn + j * 16 + lrow;
                    float bv = bias ? bias[gcol] : 0.f;
#pragma unroll
                    for (int i = 0; i < 4; i++)
#pragma unroll
                        for (int r = 0; r < 4; r++)
                            ep32[(i * 16 + lq * 4 + r) * 132 + wn + j * 16 + lrow] =
                                acc[i][j][r] + bv;
                }
            }
            __syncthreads();
#pragma unroll
            for (int c = 0; c < 8; c++) {
                int idx = tid + c * 256;
                int row = idx >> 5, l32 = idx & 31;
                int grow = bm * 128 + s * 64 + row;
                if (grow < M_real)
                    *(uint4*)((float*)C + (size_t)grow * Ncols + bn * 128 + l32 * 4) =
                        *(const uint4*)&ep32[row * 132 + l32 * 4];
            }
        }
    }
}

/* -------- MFMA flash attention v6: LDS-staged K (v4) + P-in-register (v5) --
   1D grid, XCD-swizzled: xcd = l & 7 owns 12 whole (b,h) heads.
   Block = (b,h) x 128 queries, 4 waves x 32 queries. Per 64-key tile:
   - K,V register-prefetched ONE TILE AHEAD (64-lane row scatter, issued
     before the barrier; vmcnt never drained in-loop -> loads span the
     barrier and land one full compute phase later).
   - Kt[2][64][72] double-buffered: b128 writes (lane=key row), b128
     A-fragment reads (2-way aliasing, free).  Staged ONCE per block
     (v5's per-wave direct-global K was 4x redundant + scattered: the
     regression).
   - Vt[2][64][72] double-buffered, transposed [d][kslot]: key column
     PERMUTED so the S^T output layout == PV A-operand layout.
     kslot(32a+16b+4c+r) = 32a+8c+4b+r.
   - S^T = K (Q/8)^T (Q pre-scaled in QKV GEMM epilogue). C gives lane
     (lm,lq) keys st*16+lq*4+r at q=lm -> P packed in-register with 16x
     v_cvt_pk_bf16_f32; P never touches LDS.
   - ONE barrier per tile (lgkmcnt(0) only before it).
   Scores bounded (|s|<~4): fixed-max-0 softmax; l per-lane (q=lm),
   quad-reduced + LDS broadcast once at the end.                          */
__global__ __launch_bounds__(256)
void attn_mfma(const u16* __restrict__ qkv, u16* __restrict__ out)
{
    __shared__ __align__(16) u16 Kt[2][64][72];
    __shared__ __align__(16) u16 Vt[2][64][72];
    __shared__ float Lw[4][32];

    const int l   = blockIdx.x;
    const int xcd = l & 7;
    const int j0  = l >> 3;            /* 0..107 */
    const int bh  = xcd * 12 + j0 / 9; /* 12 heads per XCD */
    const int b  = bh / H_, h = bh % H_;
    const int q0 = (j0 % 9) * 128;
    const int tid  = threadIdx.x;
    const int wave = tid >> 6, lane = tid & 63;
    const int lm = lane & 15, lq = lane >> 4;
    const int qw = q0 + wave * 32;

    /* key -> kslot permutation: key = 32a+16b+4c+r  ->  32a+8c+4b+r */
    const int vcol = (lane & 35) | ((lane & 12) << 1) | ((lane & 16) >> 2);

    /* Q fragments (B-operand: n=q=lm, k=d=lq*8+j); 1/8 scale already baked */
    bf16x8 qf[2][2];
#pragma unroll
    for (int sq = 0; sq < 2; sq++) {
        int qrow = qw + sq * 16 + lm; if (qrow > N_ - 1) qrow = N_ - 1;
        const u16* qptr = qkv + (size_t)(b * N_ + qrow) * QKVC + h * HD_;
        qf[sq][0] = *(const bf16x8*)(qptr + lq * 8);
        qf[sq][1] = *(const bf16x8*)(qptr + 32 + lq * 8);
    }

    float l_r[2] = {0.f, 0.f};
    f32x4 o_acc[2][4];
#pragma unroll
    for (int sq = 0; sq < 2; sq++)
#pragma unroll
        for (int t = 0; t < 4; t++)
            o_acc[sq][t] = (f32x4){0.f, 0.f, 0.f, 0.f};

    /* prefetch K,V tile 0 into registers (lane = key row, wave covers d-groups) */
    bf16x8 kreg[2], vreg[2];
    {
        int krow = lane; if (krow > N_ - 1) krow = N_ - 1;
        const u16* kvp = qkv + (size_t)(b * N_ + krow) * QKVC + h * HD_;
#pragma unroll
        for (int p = 0; p < 2; p++) {
            int dg = wave + p * 4;
            kreg[p] = *(const bf16x8*)(kvp + D_ + dg * 8);
            vreg[p] = *(const bf16x8*)(kvp + 2 * D_ + dg * 8);
        }
    }

    const int kTiles = (N_ + 63) / 64;   /* 17 */
    for (int kt = 0; kt < kTiles; kt++) {
        const int kbase = kt * 64;
        const int buf = kt & 1;

        /* stage K (row-major) and V (transposed, kslot-permuted columns) */
#pragma unroll
        for (int pp = 0; pp < 2; pp++) {
            int dg = wave + pp * 4;
            *(bf16x8*)&Kt[buf][lane][dg * 8] = kreg[pp];
#pragma unroll
            for (int j = 0; j < 8; j++)
                Vt[buf][dg * 8 + j][vcol] = (u16)vreg[pp][j];
        }

        /* register prefetch of next K,V tile (stays in flight across barrier) */
        if (kt + 1 < kTiles) {
            int krow = kbase + 64 + lane; if (krow > N_ - 1) krow = N_ - 1;
            const u16* kvp = qkv + (size_t)(b * N_ + krow) * QKVC + h * HD_;
#pragma unroll
            for (int pp = 0; pp < 2; pp++) {
                int dg = wave + pp * 4;
                kreg[pp] = *(const bf16x8*)(kvp + D_ + dg * 8);
                vreg[pp] = *(const bf16x8*)(kvp + 2 * D_ + dg * 8);
            }
        }

        /* LDS writes visible to all waves; global prefetch NOT drained */
        asm volatile("s_waitcnt lgkmcnt(0)" ::: "memory");
        __builtin_amdgcn_s_barrier();

        /* S^T = K (Q/8)^T : A = Kt row-frags (b128, 2-way free), B = Q regs.
           C: col=lm=q_local, row=lq*4+r -> key st*16+lq*4+r.              */
        f32x4 sc[2][4];
        __builtin_amdgcn_s_setprio(1);
#pragma unroll
        for (int st = 0; st < 4; st++) {
            bf16x8 kf0 = *(const bf16x8*)&Kt[buf][st * 16 + lm][lq * 8];
            bf16x8 kf1 = *(const bf16x8*)&Kt[buf][st * 16 + lm][32 + lq * 8];
#pragma unroll
            for (int sq = 0; sq < 2; sq++) {
                f32x4 s4 = (f32x4){0.f, 0.f, 0.f, 0.f};
                s4 = __builtin_amdgcn_mfma_f32_16x16x32_bf16(kf0, qf[sq][0], s4, 0, 0, 0);
                s4 = __builtin_amdgcn_mfma_f32_16x16x32_bf16(kf1, qf[sq][1], s4, 0, 0, 0);
                sc[sq][st] = s4;
            }
        }
        __builtin_amdgcn_s_setprio(0);

        /* softmax (fixed max 0) + in-register pack straight into the PV
           A-operand order (kslot permutation makes layouts coincide).   */
        const bool lastT = (kt == kTiles - 1);
        bf16x8 pa[2][2];
#pragma unroll
        for (int sq = 0; sq < 2; sq++) {
            union { bf16x8 v; unsigned int u[4]; } pk0, pk1;
#pragma unroll
            for (int st = 0; st < 4; st++) {
                float p0 = __expf(sc[sq][st][0]);
                float p1 = __expf(sc[sq][st][1]);
                float p2 = __expf(sc[sq][st][2]);
                float p3 = __expf(sc[sq][st][3]);
                if (lastT) {
                    const int keyb = kbase + st * 16 + lq * 4;
                    if (keyb + 0 >= N_) p0 = 0.f;
                    if (keyb + 1 >= N_) p1 = 0.f;
                    if (keyb + 2 >= N_) p2 = 0.f;
                    if (keyb + 3 >= N_) p3 = 0.f;
                }
                l_r[sq] += (p0 + p1) + (p2 + p3);
                unsigned int lo = cvtpk(p0, p1);
                unsigned int hi = cvtpk(p2, p3);
                if      (st == 0) { pk0.u[0] = lo; pk0.u[1] = hi; }
                else if (st == 1) { pk0.u[2] = lo; pk0.u[3] = hi; }
                else if (st == 2) { pk1.u[0] = lo; pk1.u[1] = hi; }
                else              { pk1.u[2] = lo; pk1.u[3] = hi; }
            }
            pa[sq][0] = pk0.v; pa[sq][1] = pk1.v;
        }

        /* PV: A = packed P regs, B = Vt rows (b128, kslot columns) */
        __builtin_amdgcn_s_setprio(1);
#pragma unroll
        for (int nt = 0; nt < 4; nt++) {
            bf16x8 vb0 = *(const bf16x8*)&Vt[buf][nt * 16 + lm][lq * 8];
            bf16x8 vb1 = *(const bf16x8*)&Vt[buf][nt * 16 + lm][32 + lq * 8];
#pragma unroll
            for (int sq = 0; sq < 2; sq++) {
                o_acc[sq][nt] = __builtin_amdgcn_mfma_f32_16x16x32_bf16(pa[sq][0], vb0, o_acc[sq][nt], 0, 0, 0);
                o_acc[sq][nt] = __builtin_amdgcn_mfma_f32_16x16x32_bf16(pa[sq][1], vb1, o_acc[sq][nt], 0, 0, 0);
            }
        }
        __builtin_amdgcn_s_setprio(0);
    }

    /* l: reduce across quads (lane holds q=sq*16+lm partial), broadcast */
#pragma unroll
    for (int sq = 0; sq < 2; sq++) {
        float l2 = l_r[sq];
        l2 += __shfl_xor(l2, 16);
        l2 += __shfl_xor(l2, 32);
        if (lq == 0) Lw[wave][sq * 16 + lm] = l2;
    }
    asm volatile("s_waitcnt lgkmcnt(0)" ::: "memory");       /* wave-local */

    /* store: O layout col=d=nt*16+lm, row=q=sq*16+lq*4+r */
#pragma unroll
    for (int sq = 0; sq < 2; sq++)
#pragma unroll
        for (int r = 0; r < 4; r++) {
            int q = qw + sq * 16 + lq * 4 + r;
            if (q < N_) {
                float inv = 1.0f / Lw[wave][sq * 16 + lq * 4 + r];
                u16* orow = out + (size_t)(b * N_ + q) * D_ + h * HD_ + lm;
#pragma unroll
                for (int nt = 0; nt < 4; nt++)
                    orow[nt * 16] = f2bf(o_acc[sq][nt][r] * inv);
            }
        }
}

extern "C" void kernel_launch(void* const* d_in, const int* in_sizes, int n_in,
                              void* d_out, int out_size, void* d_ws, size_t ws_size,
                              hipStream_t stream)
{
    const float* x      = (const float*)d_in[0];
    const float* ln_g   = (const float*)d_in[1];
    const float* ln_b   = (const float*)d_in[2];
    const float* w_qkv  = (const float*)d_in[3];
    const float* w_proj = (const float*)d_in[4];
    const float* b_proj = (const float*)d_in[5];

    u16* wqkv_b  = (u16*)d_ws;                         /* 2304*768  */
    u16* wproj_b = wqkv_b + (size_t)QKVC * D_;         /* 768*768   */
    u16* xn      = wproj_b + (size_t)D_ * D_;          /* M_PAD*768 */
    u16* qkv     = xn + (size_t)M_PAD * D_;            /* M_PAD*2304 */
    u16* attno   = xn;                                 /* alias (xn dead after QKV GEMM) */

    /* fused LN + weight convert: 8200 LN blocks + 2304 convert blocks */
    ln_f2b_kernel<<<M_REAL + (QKVC * D_ + D_ * D_) / 1024, 256, 0, stream>>>(
        x, ln_g, ln_b, xn, w_qkv, wqkv_b, w_proj, wproj_b);

    /* QKV GEMM: BM=65, BN=18; 4x2 XCD patches of 17x9 -> 1224 blocks */
    gemm_bt<u16, true><<<1224, 256, 0, stream>>>(
        xn, wqkv_b, qkv, nullptr, M_REAL, QKVC, D_,
        65, 18, 17, 9, 2);

    /* attention: 8 XCDs x 12 heads x 9 q-tiles = 864 blocks */
    attn_mfma<<<864, 256, 0, stream>>>(qkv, attno);

    /* proj GEMM: BM=65, BN=6; 8x1 XCD patches of 9x6 -> 432 blocks */
    gemm_bt<float, false><<<432, 256, 0, stream>>>(
        attno, wproj_b, (float*)d_out, b_proj, M_REAL, D_, D_,
        65, 6, 9, 6, 1);
}

// Round 3
// 211.850 us; speedup vs baseline: 1.1658x; 1.0136x over previous
//
#include <hip/hip_runtime.h>
#include <hip/hip_bf16.h>

typedef unsigned short u16;

#define B_      8
#define N_      1025
#define D_      768
#define H_      12
#define HD_     64
#define M_REAL  (B_ * N_)      /* 8200 rows */
#define M_PAD   8320           /* 65 * 128 */
#define QKVC    (3 * D_)       /* 2304 */
#define LN_BLK  (M_REAL / 4)   /* 2050 wave-per-row blocks */

typedef __attribute__((ext_vector_type(8))) short bf16x8;
typedef __attribute__((ext_vector_type(4))) float f32x4;

static __device__ __forceinline__ float bf2f(u16 u) {
    union { unsigned int i; float f; } v; v.i = ((unsigned int)u) << 16; return v.f;
}
static __device__ __forceinline__ u16 f2bf(float f) {
    union { float f; unsigned int i; } v; v.f = f;
    unsigned int x = v.i;
    return (u16)((x + 0x7fffu + ((x >> 16) & 1u)) >> 16);   /* RNE */
}
static __device__ __forceinline__ unsigned int cvtpk(float a, float b) {
    unsigned int r;
    asm volatile("v_cvt_pk_bf16_f32 %0, %1, %2" : "=v"(r) : "v"(a), "v"(b));
    return r;   /* lo = bf16(a), hi = bf16(b) */
}

/* async global->LDS, 16B per lane; LDS dest = wave-uniform base + lane*16 */
static __device__ __forceinline__ void g2l16(const u16* g, u16* l) {
    __builtin_amdgcn_global_load_lds(
        (const __attribute__((address_space(1))) unsigned int*)g,
        (__attribute__((address_space(3))) unsigned int*)l, 16, 0, 0);
}

/* ------- fused LayerNorm (wave per row) + fp32->bf16 weight convert ------- */
__global__ __launch_bounds__(256)
void ln_f2b_kernel(const float* __restrict__ x, const float* __restrict__ g,
                   const float* __restrict__ bvec, u16* __restrict__ xn,
                   const float* __restrict__ wq, u16* __restrict__ wqb,
                   const float* __restrict__ wp, u16* __restrict__ wpb)
{
    const int tid = threadIdx.x;
    if (blockIdx.x >= LN_BLK) {
        /* weight convert: 1024 elems per block */
        int i = (blockIdx.x - LN_BLK) * 1024 + tid * 4;
        const float* src; u16* dst;
        if (i < QKVC * D_) { src = wq + i; dst = wqb + i; }
        else { src = wp + (i - QKVC * D_); dst = wpb + (i - QKVC * D_); }
        float4 v = *(const float4*)src;
        dst[0] = f2bf(v.x); dst[1] = f2bf(v.y);
        dst[2] = f2bf(v.z); dst[3] = f2bf(v.w);
        return;
    }
    /* one wave per row: 768 = 3 * 64 lanes * float4, shuffle reduce, no barrier */
    const int wave = tid >> 6, lane = tid & 63;
    const int row  = blockIdx.x * 4 + wave;          /* < 8200 exactly */
    const float* xr = x + (size_t)row * D_;
    float4 v[3];
    float s = 0.f, ss = 0.f;
#pragma unroll
    for (int j = 0; j < 3; j++) {
        float4 t = *(const float4*)&xr[j * 256 + lane * 4];
        v[j] = t;
        s  += (t.x + t.y) + (t.z + t.w);
        ss += (t.x * t.x + t.y * t.y) + (t.z * t.z + t.w * t.w);
    }
#pragma unroll
    for (int off = 1; off < 64; off <<= 1) {
        s  += __shfl_xor(s,  off);
        ss += __shfl_xor(ss, off);
    }
    const float mean = s * (1.0f / D_);
    const float var  = ss * (1.0f / D_) - mean * mean;
    const float rs   = rsqrtf(var + 1e-5f);
    u16* outr = xn + (size_t)row * D_;
#pragma unroll
    for (int j = 0; j < 3; j++) {
        int c = j * 256 + lane * 4;
        float4 g4 = *(const float4*)&g[c];
        float4 b4 = *(const float4*)&bvec[c];
        u16 o[4];
        o[0] = f2bf((v[j].x - mean) * rs * g4.x + b4.x);
        o[1] = f2bf((v[j].y - mean) * rs * g4.y + b4.y);
        o[2] = f2bf((v[j].z - mean) * rs * g4.z + b4.z);
        o[3] = f2bf((v[j].w - mean) * rs * g4.w + b4.w);
        *(uint2*)&outr[c] = *(const uint2*)o;
    }
}

/* -------- GEMM: C[m][n] = sum_k A[m][k] * B[n][k] (+bias fp32) --------
   128x128 tile, BK=32, 4 waves (2x2), MFMA f32_16x16x32_bf16.
   Counted-vmcnt pipeline (T4): next tile's global_load_lds issued at the
   TOP of the iteration, s_waitcnt vmcnt(4) (current tile landed, next
   stays in flight across the barrier), raw s_barrier. Second s_barrier
   after MFMA closes the WAR window -> 2 buffers / 34KB LDS preserved
   (4 blocks/CU). No full vmcnt(0) drain in the main loop.
   ROPE fuses 2D rope (QKV output) AND the 1/8 attention scale on Q
   (exact exponent shift); XCD patch-swizzle for L2 locality.            */
template <typename OutT, bool ROPE>
__global__ __launch_bounds__(256)
void gemm_bt(const u16* __restrict__ A, const u16* __restrict__ B,
             OutT* __restrict__ C, const float* __restrict__ bias,
             int M_real, int Ncols, int K,
             int BM, int BN, int gh, int gw, int PC)
{
    const int l   = blockIdx.x;
    const int xcd = l & 7;
    const int i0  = l >> 3;
    const int pr  = xcd / PC, pc = xcd % PC;
    const int bm  = pr * gh + (i0 % gh);
    const int bn  = pc * gw + (i0 / gh);
    if (bm >= BM || bn >= BN) return;

    __shared__ __align__(16) unsigned char smem[34816];
    u16* As0 = (u16*)smem;              /* 128 x 32 */
    u16* Bs0 = (u16*)(smem + 8192);
    u16*   ep16 = (u16*)smem;           /* 128 x 136 (pad 8) */
    float* ep32 = (float*)smem;         /* 64 x 132 (pad 4)  */

    const int tid  = threadIdx.x;
    const int wave = tid >> 6, lane = tid & 63;
    const int wm   = (wave >> 1) * 64, wn = (wave & 1) * 64;
    const int lrow = lane & 15, lq = lane >> 4;
    const int lrow4 = lane >> 2, lchunk = lane & 3;

    int ar0 = bm * 128 + wave * 16 + lrow4;       if (ar0 >= M_real) ar0 = M_real - 1;
    int ar1 = bm * 128 + (wave + 4) * 16 + lrow4; if (ar1 >= M_real) ar1 = M_real - 1;
    const u16* apg0 = A + (size_t)ar0 * K + lchunk * 8;
    const u16* apg1 = A + (size_t)ar1 * K + lchunk * 8;
    const u16* bpg0 = B + (size_t)(bn * 128 + wave * 16 + lrow4) * K + lchunk * 8;
    const u16* bpg1 = B + (size_t)(bn * 128 + (wave + 4) * 16 + lrow4) * K + lchunk * 8;
    u16* asl0 = As0 + wave * 512;       u16* asl1 = As0 + (wave + 4) * 512;
    u16* bsl0 = Bs0 + wave * 512;       u16* bsl1 = Bs0 + (wave + 4) * 512;
    const int bufoff = 8192;

    f32x4 acc[4][4];
#pragma unroll
    for (int i = 0; i < 4; i++)
#pragma unroll
        for (int j = 0; j < 4; j++)
            acc[i][j] = (f32x4){0.f, 0.f, 0.f, 0.f};

    g2l16(apg0, asl0); g2l16(apg1, asl1);
    g2l16(bpg0, bsl0); g2l16(bpg1, bsl1);

    const int kTiles = K / 32;
    for (int kt = 0; kt < kTiles; kt++) {
        const int cur = kt & 1;
        /* issue next tile BEFORE the wait: its 4 loads stay in flight
           across the barrier (counted vmcnt, no full drain).           */
        if (kt + 1 < kTiles) {
            const int k1 = (kt + 1) * 32;
            const int no = (cur ^ 1) * bufoff;
            g2l16(apg0 + k1, asl0 + no); g2l16(apg1 + k1, asl1 + no);
            g2l16(bpg0 + k1, bsl0 + no); g2l16(bpg1 + k1, bsl1 + no);
            asm volatile("s_waitcnt vmcnt(4)" ::: "memory");
        } else {
            asm volatile("s_waitcnt vmcnt(0)" ::: "memory");
        }
        __builtin_amdgcn_s_barrier();      /* current tile visible to all */

        const u16* Asr = As0 + cur * bufoff;
        const u16* Bsr = Bs0 + cur * bufoff;
        bf16x8 af[4], bfr[4];
#pragma unroll
        for (int i = 0; i < 4; i++) {
            af[i]  = *(const bf16x8*)&Asr[(wm + i * 16 + lrow) * 32 + lq * 8];
            bfr[i] = *(const bf16x8*)&Bsr[(wn + i * 16 + lrow) * 32 + lq * 8];
        }
        __builtin_amdgcn_s_setprio(1);
#pragma unroll
        for (int i = 0; i < 4; i++)
#pragma unroll
            for (int j = 0; j < 4; j++)
                acc[i][j] = __builtin_amdgcn_mfma_f32_16x16x32_bf16(af[i], bfr[j], acc[i][j], 0, 0, 0);
        __builtin_amdgcn_s_setprio(0);
        /* all waves done reading buf cur (lgkm drained by MFMA deps)
           before iter kt+1 overwrites it                               */
        __builtin_amdgcn_s_barrier();
    }
    __syncthreads();

    if constexpr (sizeof(OutT) == 2) {
#pragma unroll
        for (int j = 0; j < 4; j++) {
            int gcol = bn * 128 + wn + j * 16 + lrow;
            float bv = bias ? bias[gcol] : 0.f;
            int qk = gcol / D_;
            int dh = gcol & 63;
            int half = dh >> 5, ii = (dh & 31) >> 1;
            float sgn = (dh & 1) ? 1.f : -1.f;
            float invf = exp2f(-(float)ii * 0.8304820237218406f);
#pragma unroll
            for (int i = 0; i < 4; i++)
#pragma unroll
                for (int r = 0; r < 4; r++) {
                    int grow = bm * 128 + wm + i * 16 + lq * 4 + r;
                    float val = acc[i][j][r] + bv;
                    if constexpr (ROPE) {
                        if (qk < 2) {
                            float partner = __shfl_xor(val, 1);
                            int n = grow % N_;
                            int pl = n - 1;
                            int pos = (n == 0) ? 0 : (half ? (pl & 31) : (pl >> 5));
                            float ang = (float)pos * invf;
                            val = val * __cosf(ang) + sgn * partner * __sinf(ang);
                            if (qk == 0) val *= 0.125f;   /* fold 1/sqrt(hd) into Q (exact) */
                        }
                    }
                    ep16[(wm + i * 16 + lq * 4 + r) * 136 + wn + j * 16 + lrow] = f2bf(val);
                }
        }
        __syncthreads();
#pragma unroll
        for (int c = 0; c < 8; c++) {
            int idx = tid + c * 256;
            int row = idx >> 4, l16 = idx & 15;
            int grow = bm * 128 + row;
            if (grow < M_real)
                *(uint4*)((u16*)C + (size_t)grow * Ncols + bn * 128 + l16 * 8) =
                    *(const uint4*)&ep16[row * 136 + l16 * 8];
        }
    } else {
#pragma unroll
        for (int s = 0; s < 2; s++) {
            if (s) __syncthreads();
            if (wm == s * 64) {
#pragma unroll
                for (int j = 0; j < 4; j++) {
                    int gcol = bn * 128 + wn + j * 16 + lrow;
                    float bv = bias ? bias[gcol] : 0.f;
#pragma unroll
                    for (int i = 0; i < 4; i++)
#pragma unroll
                        for (int r = 0; r < 4; r++)
                            ep32[(i * 16 + lq * 4 + r) * 132 + wn + j * 16 + lrow] =
                                acc[i][j][r] + bv;
                }
            }
            __syncthreads();
#pragma unroll
            for (int c = 0; c < 8; c++) {
                int idx = tid + c * 256;
                int row = idx >> 5, l32 = idx & 31;
                int grow = bm * 128 + s * 64 + row;
                if (grow < M_real)
                    *(uint4*)((float*)C + (size_t)grow * Ncols + bn * 128 + l32 * 4) =
                        *(const uint4*)&ep32[row * 132 + l32 * 4];
            }
        }
    }
}

/* -------- MFMA flash attention v6: LDS-staged K + P-in-register --------
   (unchanged from previous round; see comments there)                    */
__global__ __launch_bounds__(256)
void attn_mfma(const u16* __restrict__ qkv, u16* __restrict__ out)
{
    __shared__ __align__(16) u16 Kt[2][64][72];
    __shared__ __align__(16) u16 Vt[2][64][72];
    __shared__ float Lw[4][32];

    const int l   = blockIdx.x;
    const int xcd = l & 7;
    const int j0  = l >> 3;            /* 0..107 */
    const int bh  = xcd * 12 + j0 / 9; /* 12 heads per XCD */
    const int b  = bh / H_, h = bh % H_;
    const int q0 = (j0 % 9) * 128;
    const int tid  = threadIdx.x;
    const int wave = tid >> 6, lane = tid & 63;
    const int lm = lane & 15, lq = lane >> 4;
    const int qw = q0 + wave * 32;

    /* key -> kslot permutation: key = 32a+16b+4c+r  ->  32a+8c+4b+r */
    const int vcol = (lane & 35) | ((lane & 12) << 1) | ((lane & 16) >> 2);

    /* Q fragments (B-operand: n=q=lm, k=d=lq*8+j); 1/8 scale already baked */
    bf16x8 qf[2][2];
#pragma unroll
    for (int sq = 0; sq < 2; sq++) {
        int qrow = qw + sq * 16 + lm; if (qrow > N_ - 1) qrow = N_ - 1;
        const u16* qptr = qkv + (size_t)(b * N_ + qrow) * QKVC + h * HD_;
        qf[sq][0] = *(const bf16x8*)(qptr + lq * 8);
        qf[sq][1] = *(const bf16x8*)(qptr + 32 + lq * 8);
    }

    float l_r[2] = {0.f, 0.f};
    f32x4 o_acc[2][4];
#pragma unroll
    for (int sq = 0; sq < 2; sq++)
#pragma unroll
        for (int t = 0; t < 4; t++)
            o_acc[sq][t] = (f32x4){0.f, 0.f, 0.f, 0.f};

    /* prefetch K,V tile 0 into registers (lane = key row, wave covers d-groups) */
    bf16x8 kreg[2], vreg[2];
    {
        int krow = lane; if (krow > N_ - 1) krow = N_ - 1;
        const u16* kvp = qkv + (size_t)(b * N_ + krow) * QKVC + h * HD_;
#pragma unroll
        for (int p = 0; p < 2; p++) {
            int dg = wave + p * 4;
            kreg[p] = *(const bf16x8*)(kvp + D_ + dg * 8);
            vreg[p] = *(const bf16x8*)(kvp + 2 * D_ + dg * 8);
        }
    }

    const int kTiles = (N_ + 63) / 64;   /* 17 */
    for (int kt = 0; kt < kTiles; kt++) {
        const int kbase = kt * 64;
        const int buf = kt & 1;

        /* stage K (row-major) and V (transposed, kslot-permuted columns) */
#pragma unroll
        for (int pp = 0; pp < 2; pp++) {
            int dg = wave + pp * 4;
            *(bf16x8*)&Kt[buf][lane][dg * 8] = kreg[pp];
#pragma unroll
            for (int j = 0; j < 8; j++)
                Vt[buf][dg * 8 + j][vcol] = (u16)vreg[pp][j];
        }

        /* register prefetch of next K,V tile (stays in flight across barrier) */
        if (kt + 1 < kTiles) {
            int krow = kbase + 64 + lane; if (krow > N_ - 1) krow = N_ - 1;
            const u16* kvp = qkv + (size_t)(b * N_ + krow) * QKVC + h * HD_;
#pragma unroll
            for (int pp = 0; pp < 2; pp++) {
                int dg = wave + pp * 4;
                kreg[pp] = *(const bf16x8*)(kvp + D_ + dg * 8);
                vreg[pp] = *(const bf16x8*)(kvp + 2 * D_ + dg * 8);
            }
        }

        /* LDS writes visible to all waves; global prefetch NOT drained */
        asm volatile("s_waitcnt lgkmcnt(0)" ::: "memory");
        __builtin_amdgcn_s_barrier();

        /* S^T = K (Q/8)^T : A = Kt row-frags (b128, 2-way free), B = Q regs.
           C: col=lm=q_local, row=lq*4+r -> key st*16+lq*4+r.              */
        f32x4 sc[2][4];
        __builtin_amdgcn_s_setprio(1);
#pragma unroll
        for (int st = 0; st < 4; st++) {
            bf16x8 kf0 = *(const bf16x8*)&Kt[buf][st * 16 + lm][lq * 8];
            bf16x8 kf1 = *(const bf16x8*)&Kt[buf][st * 16 + lm][32 + lq * 8];
#pragma unroll
            for (int sq = 0; sq < 2; sq++) {
                f32x4 s4 = (f32x4){0.f, 0.f, 0.f, 0.f};
                s4 = __builtin_amdgcn_mfma_f32_16x16x32_bf16(kf0, qf[sq][0], s4, 0, 0, 0);
                s4 = __builtin_amdgcn_mfma_f32_16x16x32_bf16(kf1, qf[sq][1], s4, 0, 0, 0);
                sc[sq][st] = s4;
            }
        }
        __builtin_amdgcn_s_setprio(0);

        /* softmax (fixed max 0) + in-register pack straight into the PV
           A-operand order (kslot permutation makes layouts coincide).   */
        const bool lastT = (kt == kTiles - 1);
        bf16x8 pa[2][2];
#pragma unroll
        for (int sq = 0; sq < 2; sq++) {
            union { bf16x8 v; unsigned int u[4]; } pk0, pk1;
#pragma unroll
            for (int st = 0; st < 4; st++) {
                float p0 = __expf(sc[sq][st][0]);
                float p1 = __expf(sc[sq][st][1]);
                float p2 = __expf(sc[sq][st][2]);
                float p3 = __expf(sc[sq][st][3]);
                if (lastT) {
                    const int keyb = kbase + st * 16 + lq * 4;
                    if (keyb + 0 >= N_) p0 = 0.f;
                    if (keyb + 1 >= N_) p1 = 0.f;
                    if (keyb + 2 >= N_) p2 = 0.f;
                    if (keyb + 3 >= N_) p3 = 0.f;
                }
                l_r[sq] += (p0 + p1) + (p2 + p3);
                unsigned int lo = cvtpk(p0, p1);
                unsigned int hi = cvtpk(p2, p3);
                if      (st == 0) { pk0.u[0] = lo; pk0.u[1] = hi; }
                else if (st == 1) { pk0.u[2] = lo; pk0.u[3] = hi; }
                else if (st == 2) { pk1.u[0] = lo; pk1.u[1] = hi; }
                else              { pk1.u[2] = lo; pk1.u[3] = hi; }
            }
            pa[sq][0] = pk0.v; pa[sq][1] = pk1.v;
        }

        /* PV: A = packed P regs, B = Vt rows (b128, kslot columns) */
        __builtin_amdgcn_s_setprio(1);
#pragma unroll
        for (int nt = 0; nt < 4; nt++) {
            bf16x8 vb0 = *(const bf16x8*)&Vt[buf][nt * 16 + lm][lq * 8];
            bf16x8 vb1 = *(const bf16x8*)&Vt[buf][nt * 16 + lm][32 + lq * 8];
#pragma unroll
            for (int sq = 0; sq < 2; sq++) {
                o_acc[sq][nt] = __builtin_amdgcn_mfma_f32_16x16x32_bf16(pa[sq][0], vb0, o_acc[sq][nt], 0, 0, 0);
                o_acc[sq][nt] = __builtin_amdgcn_mfma_f32_16x16x32_bf16(pa[sq][1], vb1, o_acc[sq][nt], 0, 0, 0);
            }
        }
        __builtin_amdgcn_s_setprio(0);
    }

    /* l: reduce across quads (lane holds q=sq*16+lm partial), broadcast */
#pragma unroll
    for (int sq = 0; sq < 2; sq++) {
        float l2 = l_r[sq];
        l2 += __shfl_xor(l2, 16);
        l2 += __shfl_xor(l2, 32);
        if (lq == 0) Lw[wave][sq * 16 + lm] = l2;
    }
    asm volatile("s_waitcnt lgkmcnt(0)" ::: "memory");       /* wave-local */

    /* store: O layout col=d=nt*16+lm, row=q=sq*16+lq*4+r */
#pragma unroll
    for (int sq = 0; sq < 2; sq++)
#pragma unroll
        for (int r = 0; r < 4; r++) {
            int q = qw + sq * 16 + lq * 4 + r;
            if (q < N_) {
                float inv = 1.0f / Lw[wave][sq * 16 + lq * 4 + r];
                u16* orow = out + (size_t)(b * N_ + q) * D_ + h * HD_ + lm;
#pragma unroll
                for (int nt = 0; nt < 4; nt++)
                    orow[nt * 16] = f2bf(o_acc[sq][nt][r] * inv);
            }
        }
}

extern "C" void kernel_launch(void* const* d_in, const int* in_sizes, int n_in,
                              void* d_out, int out_size, void* d_ws, size_t ws_size,
                              hipStream_t stream)
{
    const float* x      = (const float*)d_in[0];
    const float* ln_g   = (const float*)d_in[1];
    const float* ln_b   = (const float*)d_in[2];
    const float* w_qkv  = (const float*)d_in[3];
    const float* w_proj = (const float*)d_in[4];
    const float* b_proj = (const float*)d_in[5];

    u16* wqkv_b  = (u16*)d_ws;                         /* 2304*768  */
    u16* wproj_b = wqkv_b + (size_t)QKVC * D_;         /* 768*768   */
    u16* xn      = wproj_b + (size_t)D_ * D_;          /* M_PAD*768 */
    u16* qkv     = xn + (size_t)M_PAD * D_;            /* M_PAD*2304 */
    u16* attno   = xn;                                 /* alias (xn dead after QKV GEMM) */

    /* fused LN (wave/row) + weight convert: 2050 + 2304 blocks */
    ln_f2b_kernel<<<LN_BLK + (QKVC * D_ + D_ * D_) / 1024, 256, 0, stream>>>(
        x, ln_g, ln_b, xn, w_qkv, wqkv_b, w_proj, wproj_b);

    /* QKV GEMM: BM=65, BN=18; 4x2 XCD patches of 17x9 -> 1224 blocks */
    gemm_bt<u16, true><<<1224, 256, 0, stream>>>(
        xn, wqkv_b, qkv, nullptr, M_REAL, QKVC, D_,
        65, 18, 17, 9, 2);

    /* attention: 8 XCDs x 12 heads x 9 q-tiles = 864 blocks */
    attn_mfma<<<864, 256, 0, stream>>>(qkv, attno);

    /* proj GEMM: BM=65, BN=6; 8x1 XCD patches of 9x6 -> 432 blocks */
    gemm_bt<float, false><<<432, 256, 0, stream>>>(
        attno, wproj_b, (float*)d_out, b_proj, M_REAL, D_, D_,
        65, 6, 9, 6, 1);
}